// Round 5
// baseline (98.604 us; speedup 1.0000x reference)
//
#include <hip/hip_runtime.h>

// Two-dispatch structure:
//   KA: fused grid — first R*16 threads build relation gate matrices;
//       remaining E threads compute state_e = block(H^4|0>, ent[e]).
//       Layer 0 uses the tensor-product shortcut (uniform input state):
//       s(i) = 0.25 * prod_q w_q[bit_q(i)],  w_q = (m00+m01, m10+m11).
//   KB: per batch element: gather state_h, apply relation block via
//       precomputed matrices (no transcendentals), dot with state_t
//       streamed directly into the accumulator (no eo register array).
//
// ws layout: relmat [R*128 floats], estate [E*32 floats]  (~13.3 MB)

struct c32 { float x, y; };

__device__ __forceinline__ c32 cmul(c32 a, c32 b) {
    return { a.x * b.x - a.y * b.y, a.x * b.y + a.y * b.x };
}
__device__ __forceinline__ c32 cadd(c32 a, c32 b) { return { a.x + b.x, a.y + b.y }; }

// PennyLane Rot(phi, theta, omega) = RZ(omega) RY(theta) RZ(phi)
__device__ __forceinline__ void make_rot(float phi, float th, float om,
                                         c32& m00, c32& m01, c32& m10, c32& m11) {
    float st, ct;
    __sincosf(0.5f * th, &st, &ct);
    float sp_, cp_;
    __sincosf(-0.5f * (phi + om), &sp_, &cp_);   // ep = exp(-0.5i(phi+omega))
    float sm_, cm_;
    __sincosf(-0.5f * (phi - om), &sm_, &cm_);   // em = exp(-0.5i(phi-omega))
    m00 = {  cp_ * ct,  sp_ * ct };
    m01 = { -cm_ * st,  sm_ * st };
    m10 = {  cm_ * st,  sm_ * st };
    m11 = {  cp_ * ct, -sp_ * ct };
}

// Apply the 12 CRot gates (layers 1..3) given params p[48] (indices 12..47).
__device__ __forceinline__ void apply_crot_layers(c32* s, const float* p) {
#pragma unroll
    for (int off = 1; off <= 3; ++off) {
#pragma unroll
        for (int q = 0; q < 4; ++q) {
            const int pi = (off * 4 + q) * 3;
            c32 m00, m01, m10, m11;
            make_rot(p[pi + 0], p[pi + 1], p[pi + 2], m00, m01, m10, m11);
            const int tq = (q + off) & 3;
            const int cmask = 1 << (3 - q);
            const int tmask = 1 << (3 - tq);
#pragma unroll
            for (int i = 0; i < 16; ++i) {
                if ((i & cmask) != 0 && (i & tmask) == 0) {
                    c32 a = s[i], b = s[i | tmask];
                    s[i]         = cadd(cmul(m00, a), cmul(m01, b));
                    s[i | tmask] = cadd(cmul(m10, a), cmul(m11, b));
                }
            }
        }
    }
}

// KA: fused relation-matrix build + entity-state compute.
__global__ __launch_bounds__(256) void ka_prep(
    const float* __restrict__ ent, const float* __restrict__ rel,
    float* __restrict__ relmat, float* __restrict__ estate, int E, int R) {
    const int idx = blockIdx.x * blockDim.x + threadIdx.x;
    const int R16 = R * 16;
    if (idx < R16) {
        const float* p = rel + (long long)(idx >> 4) * 48 + (idx & 15) * 3;
        c32 m00, m01, m10, m11;
        make_rot(p[0], p[1], p[2], m00, m01, m10, m11);
        float4* o4 = reinterpret_cast<float4*>(relmat + (long long)idx * 8);
        o4[0] = make_float4(m00.x, m00.y, m01.x, m01.y);
        o4[1] = make_float4(m10.x, m10.y, m11.x, m11.y);
        return;
    }
    const int e = idx - R16;
    if (e >= E) return;

    float pbuf[48];
    const float4* s4 = reinterpret_cast<const float4*>(ent + (long long)e * 48);
    float4* d4 = reinterpret_cast<float4*>(pbuf);
#pragma unroll
    for (int i = 0; i < 12; ++i) d4[i] = s4[i];

    // Layer 0 via tensor product: w_q = (m00+m01, m10+m11) applied to uniform
    // state; s(i) = 0.25 * w0[b0]*w1[b1]*w2[b2]*w3[b3], b_q = (i>>(3-q))&1.
    c32 w[4][2];
#pragma unroll
    for (int q = 0; q < 4; ++q) {
        c32 m00, m01, m10, m11;
        make_rot(pbuf[q * 3 + 0], pbuf[q * 3 + 1], pbuf[q * 3 + 2], m00, m01, m10, m11);
        w[q][0] = cadd(m00, m01);
        w[q][1] = cadd(m10, m11);
    }
    c32 p01[4], p23[4];
#pragma unroll
    for (int a = 0; a < 2; ++a)
#pragma unroll
        for (int bbit = 0; bbit < 2; ++bbit) {
            c32 v = cmul(w[0][a], w[1][bbit]);
            p01[a * 2 + bbit] = { 0.25f * v.x, 0.25f * v.y };   // fold in 0.25
            p23[a * 2 + bbit] = cmul(w[2][a], w[3][bbit]);
        }
    c32 s[16];
#pragma unroll
    for (int i = 0; i < 16; ++i) s[i] = cmul(p01[i >> 2], p23[i & 3]);

    apply_crot_layers(s, pbuf);

    float4* o4 = reinterpret_cast<float4*>(estate + (long long)e * 32);
#pragma unroll
    for (int i = 0; i < 8; ++i)
        o4[i] = make_float4(s[2 * i].x, s[2 * i].y, s[2 * i + 1].x, s[2 * i + 1].y);
}

// KB: gather h-state, apply relation gates, streaming dot with t-state.
__global__ __launch_bounds__(256) void kb_batch(
    const float* __restrict__ estate, const float* __restrict__ relmat,
    const int* __restrict__ h, const int* __restrict__ r, const int* __restrict__ t,
    float* __restrict__ out, int B) {
    const int b = blockIdx.x * blockDim.x + threadIdx.x;
    if (b >= B) return;

    const int hb = h[b], rb = r[b], tb = t[b];

    const float4* h4 = reinterpret_cast<const float4*>(estate + (long long)hb * 32);
    c32 sp[16];
#pragma unroll
    for (int i = 0; i < 8; ++i) {
        float4 hv = h4[i];
        sp[2 * i]     = { hv.x, hv.y };
        sp[2 * i + 1] = { hv.z, hv.w };
    }

    const float4* rm4 = reinterpret_cast<const float4*>(relmat + (long long)rb * 128);
#pragma unroll
    for (int g = 0; g < 16; ++g) {
        float4 a4 = rm4[2 * g], b4 = rm4[2 * g + 1];
        c32 m00 = { a4.x, a4.y }, m01 = { a4.z, a4.w };
        c32 m10 = { b4.x, b4.y }, m11 = { b4.z, b4.w };
        if (g < 4) {
            const int tmask = 1 << (3 - g);
#pragma unroll
            for (int i = 0; i < 16; ++i) {
                if ((i & tmask) == 0) {
                    c32 a = sp[i], bb = sp[i | tmask];
                    sp[i]         = cadd(cmul(m00, a), cmul(m01, bb));
                    sp[i | tmask] = cadd(cmul(m10, a), cmul(m11, bb));
                }
            }
        } else {
            const int off = 1 + ((g - 4) >> 2);
            const int q = (g - 4) & 3;
            const int tq = (q + off) & 3;
            const int cmask = 1 << (3 - q);
            const int tmask = 1 << (3 - tq);
#pragma unroll
            for (int i = 0; i < 16; ++i) {
                if ((i & cmask) != 0 && (i & tmask) == 0) {
                    c32 a = sp[i], bb = sp[i | tmask];
                    sp[i]         = cadd(cmul(m00, a), cmul(m01, bb));
                    sp[i | tmask] = cadd(cmul(m10, a), cmul(m11, bb));
                }
            }
        }
    }

    // Streaming dot with state_t: Re(<eo|sp>)
    const float4* t4 = reinterpret_cast<const float4*>(estate + (long long)tb * 32);
    float acc = 0.0f;
#pragma unroll
    for (int i = 0; i < 8; ++i) {
        float4 tv = t4[i];
        acc += tv.x * sp[2 * i].x + tv.y * sp[2 * i].y;
        acc += tv.z * sp[2 * i + 1].x + tv.w * sp[2 * i + 1].y;
    }
    out[b] = acc;
}

extern "C" void kernel_launch(void* const* d_in, const int* in_sizes, int n_in,
                              void* d_out, int out_size, void* d_ws, size_t ws_size,
                              hipStream_t stream) {
    const float* ent = (const float*)d_in[0];
    const float* rel = (const float*)d_in[1];
    const int*   h   = (const int*)d_in[2];
    const int*   r   = (const int*)d_in[3];
    const int*   t   = (const int*)d_in[4];
    float* out = (float*)d_out;

    const int E = in_sizes[0] / 48;
    const int R = in_sizes[1] / 48;
    const int B = in_sizes[2];

    float* relmat = (float*)d_ws;                 // R * 128 floats
    float* estate = relmat + (size_t)R * 128;     // E * 32 floats

    const int ka_threads = R * 16 + E;
    ka_prep<<<(ka_threads + 255) / 256, 256, 0, stream>>>(ent, rel, relmat, estate, E, R);
    kb_batch<<<(B + 255) / 256, 256, 0, stream>>>(estate, relmat, h, r, t, out, B);
}